// Round 11
// baseline (5594.448 us; speedup 1.0000x reference)
//
#include <hip/hip_runtime.h>
#include <cstdint>

#define B_  64
#define T_  4096
#define F_  100
#define H_  200
#define G_  600   // 3H
#define KH_ 104   // padded half2 rows of Wh (K 200 -> 208)
#define SMEM_PAD 86016   // 84KB/block: 2x84KB>160KB => no block co-residency on a CU

typedef _Float16 half2_t __attribute__((ext_vector_type(2)));

// LDS-only workgroup barrier (verified r6: removes per-step vmcnt(0) drain).
#define LDS_BARRIER() do {                                  \
    __builtin_amdgcn_sched_barrier(0);                      \
    asm volatile("s_waitcnt lgkmcnt(0)" ::: "memory");      \
    __builtin_amdgcn_s_barrier();                           \
    __builtin_amdgcn_sched_barrier(0);                      \
} while (0)

__device__ __forceinline__ float sigmoid_(float x) {
    return __builtin_amdgcn_rcpf(1.0f + __expf(-x));
}
__device__ __forceinline__ float tanh_(float x) {
    float e = __expf(-2.0f * x);
    return (1.0f - e) * __builtin_amdgcn_rcpf(1.0f + e);
}

__device__ __forceinline__ float fdot2_(half2_t a, half2_t b, float c) {
#if __has_builtin(__builtin_amdgcn_fdot2)
    return __builtin_amdgcn_fdot2(a, b, c, false);
#else
    return fmaf((float)a.x, (float)b.x, fmaf((float)a.y, (float)b.y, c));
#endif
}

// lane-pair (xor 1) sum via DPP quad_perm [1,0,3,2] — pure VALU, no LDS pipe.
__device__ __forceinline__ float dpp_xor1_add(float x) {
    int y = __builtin_amdgcn_update_dpp(0, __float_as_int(x), 0xB1, 0xF, 0xF, true);
    return x + __int_as_float(y);
}

// ---------------- Phase 0: pack Wh (f32 [200,600]) -> half2 [104][600] ----------------
__global__ void prep_whp(const float* __restrict__ Wh, half2_t* __restrict__ whp) {
    int i = blockIdx.x * 256 + threadIdx.x;
    if (i < KH_ * G_) {
        int k = i / G_, c = i - k * G_;
        half2_t v;
        v.x = (k < 100) ? (_Float16)Wh[(2 * k) * G_ + c] : (_Float16)0.f;
        v.y = (k < 100) ? (_Float16)Wh[(2 * k + 1) * G_ + c] : (_Float16)0.f;
        whp[i] = v;
    }
}

// ---------------- gi body: gi = x @ Wi + bi (session-verified structure) ----------------
// gi now stored as f16: preactivations are O(1), f16 rounding (~1e-3 abs) is
// small vs the existing 3.9e-3 absmax from f16 h/Wh. Halves the gi stream that
// crosses between co-running gi(c+1) and scan(c) — the measured +7% fused-vs-
// scan-alone interference (r8: 78MB written + 78MB read per dispatch, f32).
__device__ __forceinline__
void gi_body(char* smem, const float* __restrict__ x, const float* __restrict__ Wi,
             const float* __restrict__ bi, _Float16* __restrict__ gi,
             int t0, int TC, int blk) {
    float* xT = (float*)smem;                       // F_*68 floats = 27.2KB
    int tid = threadIdx.x;
    int row0 = blk * 64;
    int b    = row0 / TC;
    int tc0  = row0 - b * TC;
    const float* xrow = x + ((size_t)b * T_ + t0 + tc0) * F_;
    for (int i = tid; i < 64 * F_; i += 640) {
        int r = i / F_, f = i - r * F_;
        xT[f * 68 + r] = xrow[i];
    }
    __syncthreads();
    int col = tid < G_ ? tid : G_ - 1;
    float acc[64];
    #pragma unroll
    for (int r = 0; r < 64; ++r) acc[r] = 0.f;
    for (int f = 0; f < F_; ++f) {
        float wi = Wi[f * G_ + col];
        const float4* xf = (const float4*)&xT[f * 68];
        #pragma unroll
        for (int q = 0; q < 16; ++q) {
            float4 v = xf[q];
            acc[4*q+0] = fmaf(v.x, wi, acc[4*q+0]);
            acc[4*q+1] = fmaf(v.y, wi, acc[4*q+1]);
            acc[4*q+2] = fmaf(v.z, wi, acc[4*q+2]);
            acc[4*q+3] = fmaf(v.w, wi, acc[4*q+3]);
        }
    }
    if (tid < G_) {
        float bv = bi[col];
        _Float16* grow = gi + (size_t)row0 * G_ + col;
        #pragma unroll 4
        for (int r = 0; r < 64; ++r) grow[(size_t)r * G_] = (_Float16)(acc[r] + bv);
    }
}

// ---------------- scan body: r6/r8 champion (gi reads now f16) ----------------
// Step = ~2530 cyc, pinned across 6 structural variants: ~1040 cyc dot-issue
// (near the 937-cyc floor of 60000 lane-dots/step at the measured ~4cyc
// effective wave-dot rate) + ~1500 cyc inherent tail (two LDS exchanges with
// mandatory barriers + elementwise chain). Do not restructure further.
__device__ __forceinline__
void scan_body(char* smem, const _Float16* __restrict__ gi, const half2_t* __restrict__ whp,
               const float* __restrict__ bhn, _Float16* __restrict__ hs,
               float* __restrict__ hstate, int TC, int first, int b) {
    _Float16* h_h  = (_Float16*)smem;               // 208 f16 (pad to 448B)
    float*    A_lds = (float*)(smem + 448);         // 600 f32
    float*    Hn_lds = (float*)(smem + 2848);       // 200 f32
    int tid = threadIdx.x;
    int p = tid >> 1;                 // pair id, [0,320)
    int s = tid & 1;                  // K-half
    if (p >= 300) p = 299;            // clamp: threads 600..639 duplicate, benign
    int c0 = p;
    int c1 = p + 300;

    half2_t wa[52], wb[52];           // 104 regs of packed f16 weights
    #pragma unroll
    for (int j = 0; j < 52; ++j) {
        wa[j] = whp[(52 * s + j) * G_ + c0];
        wb[j] = whp[(52 * s + j) * G_ + c1];
    }
    float bhn_r = (c1 >= 2*H_) ? bhn[c1 - 2*H_] : 0.f;

    float hj = 0.f;
    if (tid < H_) {
        hj = first ? 0.f : hstate[b * H_ + tid];
        h_h[tid] = (_Float16)hj;
    }
    if (tid >= H_ && tid < 208) h_h[tid] = (_Float16)0.f;
    __syncthreads();

    const _Float16* girow = gi + (size_t)b * TC * G_;
    _Float16* hsb = hs + (size_t)b * TC * H_;

    float g0 = 0.f, g1 = 0.f;
    if (s == 0) { g0 = (float)girow[c0]; g1 = (float)girow[c1]; }   // prefetch step 0
    for (int tc = 0; tc < TC; ++tc) {
        float g0n = 0.f, g1n = 0.f;                       // prefetch next step
        if (s == 0 && tc + 1 < TC) {
            const _Float16* gnx = girow + (size_t)(tc + 1) * G_;
            g0n = (float)gnx[c0];
            g1n = (float)gnx[c1];
        }
        float a0 = 0.f, a1 = 0.f, a2 = 0.f, a3 = 0.f;
        float b0 = 0.f, b1 = 0.f, b2 = 0.f, b3 = 0.f;
        const float4* h4 = (const float4*)(h_h + 104 * s);   // 16B-aligned
        #pragma unroll
        for (int q = 0; q < 13; ++q) {
            float4 hv = h4[q];                   // 8 halves = 4 half2
            half2_t* hp = (half2_t*)&hv;
            a0 = fdot2_(hp[0], wa[4*q+0], a0);
            a1 = fdot2_(hp[1], wa[4*q+1], a1);
            a2 = fdot2_(hp[2], wa[4*q+2], a2);
            a3 = fdot2_(hp[3], wa[4*q+3], a3);
            b0 = fdot2_(hp[0], wb[4*q+0], b0);
            b1 = fdot2_(hp[1], wb[4*q+1], b1);
            b2 = fdot2_(hp[2], wb[4*q+2], b2);
            b3 = fdot2_(hp[3], wb[4*q+3], b3);
        }
        float accA = dpp_xor1_add((a0 + a1) + (a2 + a3));   // sum across lane pair
        float accB = dpp_xor1_add((b0 + b1) + (b2 + b3));
        if (s == 0) {
            A_lds[c0] = g0 + accA;               // c0 in [0,300): r or z cols
            if (c1 < 2*H_) {
                A_lds[c1] = g1 + accB;           // z cols 300..399
            } else {
                A_lds[c1] = g1;                  // n cols 400..599
                Hn_lds[c1 - 2*H_] = accB + bhn_r;
            }
        }
        LDS_BARRIER();                // LDS-visibility only: VMEM stays in flight
        if (tid < H_) {
            float r = sigmoid_(A_lds[tid]);
            float z = sigmoid_(A_lds[H_ + tid]);
            float n = tanh_(A_lds[2*H_ + tid] + r * Hn_lds[tid]);
            hj = n + z * (hj - n);
            h_h[tid] = (_Float16)hj;
            hsb[(size_t)tc * H_ + tid] = (_Float16)hj;   // fire-and-forget
        }
        LDS_BARRIER();
        g0 = g0n; g1 = g1n;
    }
    if (tid < H_) hstate[b * H_ + tid] = hj;
}

// ---------------- outproj body ----------------
__device__ __forceinline__
void out_body(const _Float16* __restrict__ hs, const float* __restrict__ Wo,
              const float* __restrict__ bo, float* __restrict__ out,
              int t0, int TC, int blk) {
    int r = blk * 640 + threadIdx.x;
    if (r >= B_ * TC) return;
    int b = r / TC, tc = r - b * TC;
    const float4* h4 = (const float4*)(hs + (size_t)r * H_);
    float acc = 0.f;
    #pragma unroll
    for (int q = 0; q < 25; ++q) {
        float4 v = h4[q];
        const _Float16* hp = (const _Float16*)&v;
        #pragma unroll
        for (int j = 0; j < 8; ++j)
            acc = fmaf((float)hp[j], Wo[q * 8 + j], acc);
    }
    out[(size_t)b * T_ + t0 + tc] = acc + bo[0];
}

// ---------------- Fused per-chunk kernel: scan(c) || gi(c+1) || outproj(c-1) ----------------
// Blocks 0..63: scan on 64 CUs. Blocks 64..: gi for next chunk, then outproj
// for previous. 84KB LDS pad keeps roles on disjoint CUs (verified r8: fused
// dispatch = scan-alone + ~36us; gi/outproj fully hidden).
__global__ __launch_bounds__(640, 1)
void fused_kernel(const float* __restrict__ x, const float* __restrict__ Wi,
                  const float* __restrict__ bi,
                  const _Float16* __restrict__ gi_scan, _Float16* __restrict__ gi_next,
                  const half2_t* __restrict__ whp, const float* __restrict__ bhn,
                  _Float16* __restrict__ hs_w, const _Float16* __restrict__ hs_r,
                  float* __restrict__ hstate,
                  const float* __restrict__ Wo, const float* __restrict__ bo,
                  float* __restrict__ out,
                  int c, int nc, int TC) {
    __shared__ __align__(16) char smem[SMEM_PAD];
    int blk = blockIdx.x;
    int gi_blocks = (B_ * TC) / 64;
    if (blk < 64) {
        scan_body(smem, gi_scan, whp, bhn, hs_w, hstate, TC, c == 0, blk);
    } else if (blk < 64 + gi_blocks) {
        if (c + 1 < nc)
            gi_body(smem, x, Wi, bi, gi_next, (c + 1) * TC, TC, blk - 64);
    } else {
        if (c >= 1)
            out_body(hs_r, Wo, bo, out, (c - 1) * TC, TC, blk - 64 - gi_blocks);
    }
}

// standalone gi for chunk 0 (full GPU, before the pipeline starts)
__global__ __launch_bounds__(640, 1)
void gi_kernel(const float* __restrict__ x, const float* __restrict__ Wi,
               const float* __restrict__ bi, _Float16* __restrict__ gi,
               int t0, int TC) {
    __shared__ __align__(16) char smem[F_ * 68 * 4];
    gi_body(smem, x, Wi, bi, gi, t0, TC, blockIdx.x);
}

// standalone outproj for the last chunk
__global__ __launch_bounds__(256, 4)
void outproj_kernel(const _Float16* __restrict__ hs, const float* __restrict__ Wo,
                    const float* __restrict__ bo, float* __restrict__ out,
                    int t0, int TC) {
    int r = blockIdx.x * 256 + threadIdx.x;
    if (r >= B_ * TC) return;
    int b = r / TC, tc = r - b * TC;
    const float4* h4 = (const float4*)(hs + (size_t)r * H_);
    float acc = 0.f;
    #pragma unroll
    for (int q = 0; q < 25; ++q) {
        float4 v = h4[q];
        const _Float16* hp = (const _Float16*)&v;
        #pragma unroll
        for (int j = 0; j < 8; ++j)
            acc = fmaf((float)hp[j], Wo[q * 8 + j], acc);
    }
    out[(size_t)b * T_ + t0 + tc] = acc + bo[0];
}

extern "C" void kernel_launch(void* const* d_in, const int* in_sizes, int n_in,
                              void* d_out, int out_size, void* d_ws, size_t ws_size,
                              hipStream_t stream) {
    const float* x   = (const float*)d_in[0];
    const float* Wi  = (const float*)d_in[1];
    const float* bi  = (const float*)d_in[2];
    const float* Wh  = (const float*)d_in[3];
    const float* bhn = (const float*)d_in[4];
    const float* Wo  = (const float*)d_in[5];
    const float* bo  = (const float*)d_in[6];
    float* out = (float*)d_out;

    const size_t hstate_b = (size_t)B_ * H_ * sizeof(float);
    const size_t whp_b    = (size_t)KH_ * G_ * sizeof(half2_t);
    // ws layout (ping-pong): [gi0][gi1][hs0][hs1][hstate][whp]; gi now f16.
    // TC=512 (r8 champion chunking: 8 chunks — r10 measured TC=1024 worse).
    int TC = 512;
    while (TC > 64 &&
           2 * (size_t)B_ * TC * (G_ * 2 + H_ * 2) + hstate_b + whp_b > ws_size)
        TC >>= 1;
    int nc = T_ / TC;
    char* p = (char*)d_ws;
    const size_t gi_b = (size_t)B_ * TC * G_ * sizeof(_Float16);
    const size_t hs_b = (size_t)B_ * TC * H_ * sizeof(_Float16);
    _Float16* gi0    = (_Float16*)p;         p += gi_b;
    _Float16* gi1    = (_Float16*)p;         p += gi_b;
    _Float16* hs0    = (_Float16*)p;         p += hs_b;
    _Float16* hs1    = (_Float16*)p;         p += hs_b;
    float*    hstate = (float*)p;            p += hstate_b;
    half2_t*  whp    = (half2_t*)p;

    prep_whp<<<dim3((KH_ * G_ + 255) / 256), dim3(256), 0, stream>>>(Wh, whp);

    int gi_blocks  = (B_ * TC) / 64;
    int out_blocks = (B_ * TC + 639) / 640;
    int grid = 64 + gi_blocks + out_blocks;

    // chunk 0 gi on the full GPU
    gi_kernel<<<dim3(gi_blocks), dim3(640), 0, stream>>>(x, Wi, bi, gi0, 0, TC);

    for (int c = 0; c < nc; ++c) {
        _Float16* gi_s = (c & 1) ? gi1 : gi0;          // scan reads chunk c
        _Float16* gi_w = (c & 1) ? gi0 : gi1;          // gi writes chunk c+1
        _Float16* hs_w = (c & 1) ? hs1 : hs0;          // scan writes chunk c
        _Float16* hs_r = (c & 1) ? hs0 : hs1;          // outproj reads chunk c-1
        fused_kernel<<<dim3(grid), dim3(640), 0, stream>>>(
            x, Wi, bi, gi_s, gi_w, whp, bhn, hs_w, hs_r, hstate,
            Wo, bo, out, c, nc, TC);
    }
    _Float16* hs_last = ((nc - 1) & 1) ? hs1 : hs0;
    outproj_kernel<<<dim3((B_ * TC + 255) / 256), dim3(256), 0, stream>>>(
        hs_last, Wo, bo, out, (nc - 1) * TC, TC);
}

// Round 12
// 4665.748 us; speedup vs baseline: 1.1990x; 1.1990x over previous
//
#include <hip/hip_runtime.h>
#include <cstdint>

#define B_  64
#define T_  4096
#define F_  100
#define H_  200
#define G_  600   // 3H
#define KH_ 104   // padded half2 rows of Wh (K 200 -> 208)
#define SMEM_PAD 86016   // 84KB/block: 2x84KB>160KB => no block co-residency on a CU

typedef _Float16 half2_t __attribute__((ext_vector_type(2)));

// LDS-only workgroup barrier (verified r6: removes per-step vmcnt(0) drain).
#define LDS_BARRIER() do {                                  \
    __builtin_amdgcn_sched_barrier(0);                      \
    asm volatile("s_waitcnt lgkmcnt(0)" ::: "memory");      \
    __builtin_amdgcn_s_barrier();                           \
    __builtin_amdgcn_sched_barrier(0);                      \
} while (0)

__device__ __forceinline__ float sigmoid_(float x) {
    return __builtin_amdgcn_rcpf(1.0f + __expf(-x));
}
__device__ __forceinline__ float tanh_(float x) {
    float e = __expf(-2.0f * x);
    return (1.0f - e) * __builtin_amdgcn_rcpf(1.0f + e);
}

__device__ __forceinline__ float fdot2_(half2_t a, half2_t b, float c) {
#if __has_builtin(__builtin_amdgcn_fdot2)
    return __builtin_amdgcn_fdot2(a, b, c, false);
#else
    return fmaf((float)a.x, (float)b.x, fmaf((float)a.y, (float)b.y, c));
#endif
}

// lane-pair (xor 1) sum via DPP quad_perm [1,0,3,2] — pure VALU, no LDS pipe.
__device__ __forceinline__ float dpp_xor1_add(float x) {
    int y = __builtin_amdgcn_update_dpp(0, __float_as_int(x), 0xB1, 0xF, 0xF, true);
    return x + __int_as_float(y);
}

// ---------------- Phase 0: pack Wh (f32 [200,600]) -> half2 [104][600] ----------------
__global__ void prep_whp(const float* __restrict__ Wh, half2_t* __restrict__ whp) {
    int i = blockIdx.x * 256 + threadIdx.x;
    if (i < KH_ * G_) {
        int k = i / G_, c = i - k * G_;
        half2_t v;
        v.x = (k < 100) ? (_Float16)Wh[(2 * k) * G_ + c] : (_Float16)0.f;
        v.y = (k < 100) ? (_Float16)Wh[(2 * k + 1) * G_ + c] : (_Float16)0.f;
        whp[i] = v;
    }
}

// ---------------- gi body: gi = x @ Wi + bi (f32 — r11 proved f16 gi slower) ----------------
__device__ __forceinline__
void gi_body(char* smem, const float* __restrict__ x, const float* __restrict__ Wi,
             const float* __restrict__ bi, float* __restrict__ gi,
             int t0, int TC, int blk) {
    float* xT = (float*)smem;                       // F_*68 floats = 27.2KB
    int tid = threadIdx.x;
    int row0 = blk * 64;
    int b    = row0 / TC;
    int tc0  = row0 - b * TC;
    const float* xrow = x + ((size_t)b * T_ + t0 + tc0) * F_;
    for (int i = tid; i < 64 * F_; i += 640) {
        int r = i / F_, f = i - r * F_;
        xT[f * 68 + r] = xrow[i];
    }
    __syncthreads();
    int col = tid < G_ ? tid : G_ - 1;
    float acc[64];
    #pragma unroll
    for (int r = 0; r < 64; ++r) acc[r] = 0.f;
    for (int f = 0; f < F_; ++f) {
        float wi = Wi[f * G_ + col];
        const float4* xf = (const float4*)&xT[f * 68];
        #pragma unroll
        for (int q = 0; q < 16; ++q) {
            float4 v = xf[q];
            acc[4*q+0] = fmaf(v.x, wi, acc[4*q+0]);
            acc[4*q+1] = fmaf(v.y, wi, acc[4*q+1]);
            acc[4*q+2] = fmaf(v.z, wi, acc[4*q+2]);
            acc[4*q+3] = fmaf(v.w, wi, acc[4*q+3]);
        }
    }
    if (tid < G_) {
        float bv = bi[col];
        float* grow = gi + (size_t)row0 * G_ + col;
        #pragma unroll 4
        for (int r = 0; r < 64; ++r) grow[(size_t)r * G_] = acc[r] + bv;
    }
}

// ---------------- scan body: r6/r8 champion, verbatim ----------------
// Step = ~2530 cyc, pinned across 6 structural variants: ~1040 cyc dot-issue
// (near the 937-cyc floor of 60000 lane-dots/step at the measured ~4cyc
// effective wave-dot rate) + ~1500 cyc inherent tail (two LDS exchanges with
// mandatory barriers + elementwise chain). Do not restructure further.
__device__ __forceinline__
void scan_body(char* smem, const float* __restrict__ gi, const half2_t* __restrict__ whp,
               const float* __restrict__ bhn, _Float16* __restrict__ hs,
               float* __restrict__ hstate, int TC, int first, int b) {
    _Float16* h_h  = (_Float16*)smem;               // 208 f16 (pad to 448B)
    float*    A_lds = (float*)(smem + 448);         // 600 f32
    float*    Hn_lds = (float*)(smem + 2848);       // 200 f32
    int tid = threadIdx.x;
    int p = tid >> 1;                 // pair id, [0,320)
    int s = tid & 1;                  // K-half
    if (p >= 300) p = 299;            // clamp: threads 600..639 duplicate, benign
    int c0 = p;
    int c1 = p + 300;

    half2_t wa[52], wb[52];           // 104 regs of packed f16 weights
    #pragma unroll
    for (int j = 0; j < 52; ++j) {
        wa[j] = whp[(52 * s + j) * G_ + c0];
        wb[j] = whp[(52 * s + j) * G_ + c1];
    }
    float bhn_r = (c1 >= 2*H_) ? bhn[c1 - 2*H_] : 0.f;

    float hj = 0.f;
    if (tid < H_) {
        hj = first ? 0.f : hstate[b * H_ + tid];
        h_h[tid] = (_Float16)hj;
    }
    if (tid >= H_ && tid < 208) h_h[tid] = (_Float16)0.f;
    __syncthreads();

    const float* girow = gi + (size_t)b * TC * G_;
    _Float16* hsb = hs + (size_t)b * TC * H_;

    float g0 = 0.f, g1 = 0.f;
    if (s == 0) { g0 = girow[c0]; g1 = girow[c1]; }       // prefetch step 0
    for (int tc = 0; tc < TC; ++tc) {
        float g0n = 0.f, g1n = 0.f;                       // prefetch next step
        if (s == 0 && tc + 1 < TC) {
            g0n = girow[(size_t)(tc + 1) * G_ + c0];
            g1n = girow[(size_t)(tc + 1) * G_ + c1];
        }
        float a0 = 0.f, a1 = 0.f, a2 = 0.f, a3 = 0.f;
        float b0 = 0.f, b1 = 0.f, b2 = 0.f, b3 = 0.f;
        const float4* h4 = (const float4*)(h_h + 104 * s);   // 16B-aligned
        #pragma unroll
        for (int q = 0; q < 13; ++q) {
            float4 hv = h4[q];                   // 8 halves = 4 half2
            half2_t* hp = (half2_t*)&hv;
            a0 = fdot2_(hp[0], wa[4*q+0], a0);
            a1 = fdot2_(hp[1], wa[4*q+1], a1);
            a2 = fdot2_(hp[2], wa[4*q+2], a2);
            a3 = fdot2_(hp[3], wa[4*q+3], a3);
            b0 = fdot2_(hp[0], wb[4*q+0], b0);
            b1 = fdot2_(hp[1], wb[4*q+1], b1);
            b2 = fdot2_(hp[2], wb[4*q+2], b2);
            b3 = fdot2_(hp[3], wb[4*q+3], b3);
        }
        float accA = dpp_xor1_add((a0 + a1) + (a2 + a3));   // sum across lane pair
        float accB = dpp_xor1_add((b0 + b1) + (b2 + b3));
        if (s == 0) {
            A_lds[c0] = g0 + accA;               // c0 in [0,300): r or z cols
            if (c1 < 2*H_) {
                A_lds[c1] = g1 + accB;           // z cols 300..399
            } else {
                A_lds[c1] = g1;                  // n cols 400..599
                Hn_lds[c1 - 2*H_] = accB + bhn_r;
            }
        }
        LDS_BARRIER();                // LDS-visibility only: VMEM stays in flight
        if (tid < H_) {
            float r = sigmoid_(A_lds[tid]);
            float z = sigmoid_(A_lds[H_ + tid]);
            float n = tanh_(A_lds[2*H_ + tid] + r * Hn_lds[tid]);
            hj = n + z * (hj - n);
            h_h[tid] = (_Float16)hj;
            hsb[(size_t)tc * H_ + tid] = (_Float16)hj;   // fire-and-forget
        }
        LDS_BARRIER();
        g0 = g0n; g1 = g1n;
    }
    if (tid < H_) hstate[b * H_ + tid] = hj;
}

// ---------------- outproj body ----------------
__device__ __forceinline__
void out_body(const _Float16* __restrict__ hs, const float* __restrict__ Wo,
              const float* __restrict__ bo, float* __restrict__ out,
              int t0, int TC, int blk) {
    int r = blk * 640 + threadIdx.x;
    if (r >= B_ * TC) return;
    int b = r / TC, tc = r - b * TC;
    const float4* h4 = (const float4*)(hs + (size_t)r * H_);
    float acc = 0.f;
    #pragma unroll
    for (int q = 0; q < 25; ++q) {
        float4 v = h4[q];
        const _Float16* hp = (const _Float16*)&v;
        #pragma unroll
        for (int j = 0; j < 8; ++j)
            acc = fmaf((float)hp[j], Wo[q * 8 + j], acc);
    }
    out[(size_t)b * T_ + t0 + tc] = acc + bo[0];
}

// ---------------- Fused per-chunk kernel: scan(c) || gi(c+1) || outproj(c-1) ----------------
// Blocks 0..63: scan on 64 CUs. Blocks 64..: gi for next chunk, then outproj
// for previous. 84KB LDS pad keeps roles on disjoint CUs (verified r8: fused
// dispatch = scan-alone + ~36us; gi/outproj fully hidden).
__global__ __launch_bounds__(640, 1)
void fused_kernel(const float* __restrict__ x, const float* __restrict__ Wi,
                  const float* __restrict__ bi,
                  const float* __restrict__ gi_scan, float* __restrict__ gi_next,
                  const half2_t* __restrict__ whp, const float* __restrict__ bhn,
                  _Float16* __restrict__ hs_w, const _Float16* __restrict__ hs_r,
                  float* __restrict__ hstate,
                  const float* __restrict__ Wo, const float* __restrict__ bo,
                  float* __restrict__ out,
                  int c, int nc, int TC) {
    __shared__ __align__(16) char smem[SMEM_PAD];
    int blk = blockIdx.x;
    int gi_blocks = (B_ * TC) / 64;
    if (blk < 64) {
        scan_body(smem, gi_scan, whp, bhn, hs_w, hstate, TC, c == 0, blk);
    } else if (blk < 64 + gi_blocks) {
        if (c + 1 < nc)
            gi_body(smem, x, Wi, bi, gi_next, (c + 1) * TC, TC, blk - 64);
    } else {
        if (c >= 1)
            out_body(hs_r, Wo, bo, out, (c - 1) * TC, TC, blk - 64 - gi_blocks);
    }
}

// standalone gi for chunk 0 (full GPU, before the pipeline starts)
__global__ __launch_bounds__(640, 1)
void gi_kernel(const float* __restrict__ x, const float* __restrict__ Wi,
               const float* __restrict__ bi, float* __restrict__ gi,
               int t0, int TC) {
    __shared__ __align__(16) char smem[F_ * 68 * 4];
    gi_body(smem, x, Wi, bi, gi, t0, TC, blockIdx.x);
}

// standalone outproj for the last chunk
__global__ __launch_bounds__(256, 4)
void outproj_kernel(const _Float16* __restrict__ hs, const float* __restrict__ Wo,
                    const float* __restrict__ bo, float* __restrict__ out,
                    int t0, int TC) {
    int r = blockIdx.x * 256 + threadIdx.x;
    if (r >= B_ * TC) return;
    int b = r / TC, tc = r - b * TC;
    const float4* h4 = (const float4*)(hs + (size_t)r * H_);
    float acc = 0.f;
    #pragma unroll
    for (int q = 0; q < 25; ++q) {
        float4 v = h4[q];
        const _Float16* hp = (const _Float16*)&v;
        #pragma unroll
        for (int j = 0; j < 8; ++j)
            acc = fmaf((float)hp[j], Wo[q * 8 + j], acc);
    }
    out[(size_t)b * T_ + t0 + tc] = acc + bo[0];
}

extern "C" void kernel_launch(void* const* d_in, const int* in_sizes, int n_in,
                              void* d_out, int out_size, void* d_ws, size_t ws_size,
                              hipStream_t stream) {
    const float* x   = (const float*)d_in[0];
    const float* Wi  = (const float*)d_in[1];
    const float* bi  = (const float*)d_in[2];
    const float* Wh  = (const float*)d_in[3];
    const float* bhn = (const float*)d_in[4];
    const float* Wo  = (const float*)d_in[5];
    const float* bo  = (const float*)d_in[6];
    float* out = (float*)d_out;

    const size_t hstate_b = (size_t)B_ * H_ * sizeof(float);
    const size_t whp_b    = (size_t)KH_ * G_ * sizeof(half2_t);
    // ws layout (ping-pong): [gi0][gi1][hs0][hs1][hstate][whp]
    // TC=512 (r8 champion; r10: TC=1024 worse, r11: f16 gi worse).
    int TC = 512;
    while (TC > 64 &&
           2 * (size_t)B_ * TC * (G_ * 4 + H_ * 2) + hstate_b + whp_b > ws_size)
        TC >>= 1;
    int nc = T_ / TC;
    char* p = (char*)d_ws;
    const size_t gi_b = (size_t)B_ * TC * G_ * sizeof(float);
    const size_t hs_b = (size_t)B_ * TC * H_ * sizeof(_Float16);
    float*    gi0    = (float*)p;            p += gi_b;
    float*    gi1    = (float*)p;            p += gi_b;
    _Float16* hs0    = (_Float16*)p;         p += hs_b;
    _Float16* hs1    = (_Float16*)p;         p += hs_b;
    float*    hstate = (float*)p;            p += hstate_b;
    half2_t*  whp    = (half2_t*)p;

    prep_whp<<<dim3((KH_ * G_ + 255) / 256), dim3(256), 0, stream>>>(Wh, whp);

    int gi_blocks  = (B_ * TC) / 64;
    int out_blocks = (B_ * TC + 639) / 640;
    int grid = 64 + gi_blocks + out_blocks;

    // chunk 0 gi on the full GPU
    gi_kernel<<<dim3(gi_blocks), dim3(640), 0, stream>>>(x, Wi, bi, gi0, 0, TC);

    for (int c = 0; c < nc; ++c) {
        float*    gi_s = (c & 1) ? gi1 : gi0;          // scan reads chunk c
        float*    gi_w = (c & 1) ? gi0 : gi1;          // gi writes chunk c+1
        _Float16* hs_w = (c & 1) ? hs1 : hs0;          // scan writes chunk c
        _Float16* hs_r = (c & 1) ? hs0 : hs1;          // outproj reads chunk c-1
        fused_kernel<<<dim3(grid), dim3(640), 0, stream>>>(
            x, Wi, bi, gi_s, gi_w, whp, bhn, hs_w, hs_r, hstate,
            Wo, bo, out, c, nc, TC);
    }
    _Float16* hs_last = ((nc - 1) & 1) ? hs1 : hs0;
    outproj_kernel<<<dim3((B_ * TC + 255) / 256), dim3(256), 0, stream>>>(
        hs_last, Wo, bo, out, (nc - 1) * TC, TC);
}